// Round 15
// baseline (553.513 us; speedup 1.0000x reference)
//
#include <hip/hip_runtime.h>
#include <hip/hip_bf16.h>
#include <stdint.h>

#define TOK   16384
#define DIM   256
#define HIDN  1024
#define OUTD  256
#define NEXP  8
#define NSH   3
#define NSLOT 11
#define TM    64
#define NCH   32      // hidden chunks of 32 cols

typedef short bf16x8  __attribute__((ext_vector_type(8)));
typedef float f32x4   __attribute__((ext_vector_type(4)));
typedef short short4v __attribute__((ext_vector_type(4)));

// ---- workspace layout (bytes) ----
constexpr size_t XB_OFF   = 0;                                        // T*D bf16
constexpr size_t W1P_OFF  = XB_OFF  + (size_t)TOK*DIM*2;
constexpr size_t W2P_OFF  = W1P_OFF + (size_t)NSLOT*DIM*HIDN*2;
constexpr size_t WTS_OFF  = W2P_OFF + (size_t)NSLOT*HIDN*OUTD*2;
constexpr size_t IDS_OFF  = WTS_OFF + (size_t)TOK*2*4;
constexpr size_t CNT_OFF  = IDS_OFF + (size_t)TOK*2*4;
constexpr size_t LTOK_OFF = CNT_OFF + 256;
constexpr size_t LW_OFF   = LTOK_OFF + (size_t)NEXP*TOK*4;
constexpr size_t WS_NEED  = LW_OFF + (size_t)NEXP*TOK*4;

__device__ __forceinline__ unsigned short f2bf(float f) {
    __hip_bfloat16 h = __float2bfloat16(f);
    return *reinterpret_cast<unsigned short*>(&h);
}

__device__ __forceinline__ f32x4 mfma16(bf16x8 a, bf16x8 b, f32x4 c) {
    return __builtin_amdgcn_mfma_f32_16x16x32_bf16(a, b, c, 0, 0, 0);
}

// async global->LDS: 16B/lane; global src per-lane, LDS dst uniform base.
__device__ __forceinline__ void gload_lds16(const void* g, void* l) {
    __builtin_amdgcn_global_load_lds(
        (const __attribute__((address_space(1))) unsigned int*)g,
        (__attribute__((address_space(3))) unsigned int*)l, 16, 0, 0);
}

// H tile 64x32 bf16 (row stride 64B = 16 banks). Rotation by
// ((r>>1)+(r>>2))&3 16B-slots: rows {r,r+4,r+8,r+12} (write pattern) get 4
// DISTINCT slots -> conflict-free writes; 16 consecutive rows (read pattern)
// land 2 even + 2 odd rows per slot -> 2-way reads (free, m136).
__device__ __forceinline__ int hoff(int row, int cb) {
    int rot = ((row >> 1) + (row >> 2)) & 3;
    return (row << 6) + ((((cb >> 4) + rot) & 3) << 4) + (cb & 15);
}

// ---- fused: fp32->bf16 convert of X + fp32-exact gating (one X pass) ----
__global__ __launch_bounds__(256) void k_prep(
    const float* __restrict__ x, const float* __restrict__ gw,
    const float* __restrict__ gb, short* __restrict__ xb,
    float* __restrict__ wts, int* __restrict__ ids) {
    int wid = threadIdx.x >> 6, lane = threadIdx.x & 63;
    int t = blockIdx.x * 4 + wid;
    const float* xr = x + (size_t)t * DIM;
    {
        float4 v = reinterpret_cast<const float4*>(xr)[lane];
        short4v o;
        o[0] = (short)f2bf(v.x); o[1] = (short)f2bf(v.y);
        o[2] = (short)f2bf(v.z); o[3] = (short)f2bf(v.w);
        reinterpret_cast<short4v*>(xb + (size_t)t * DIM)[lane] = o;
    }
    float acc[NEXP] = {0.f,0.f,0.f,0.f,0.f,0.f,0.f,0.f};
    #pragma unroll
    for (int i = 0; i < DIM/64; ++i) {
        int d = i*64 + lane;
        float xv = xr[d];
        const float* g = gw + (size_t)d * NEXP;
        #pragma unroll
        for (int e = 0; e < NEXP; ++e) acc[e] = fmaf(xv, g[e], acc[e]);
    }
    #pragma unroll
    for (int off = 32; off; off >>= 1) {
        #pragma unroll
        for (int e = 0; e < NEXP; ++e) acc[e] += __shfl_xor(acc[e], off, 64);
    }
    if (lane == 0) {
        float l[NEXP];
        #pragma unroll
        for (int e = 0; e < NEXP; ++e) l[e] = acc[e] + gb[e];
        int e0 = 0; float v0 = l[0];
        #pragma unroll
        for (int e = 1; e < NEXP; ++e) if (l[e] > v0) { v0 = l[e]; e0 = e; }
        int e1 = -1; float v1 = -1e30f;
        #pragma unroll
        for (int e = 0; e < NEXP; ++e) if (e != e0 && l[e] > v1) { v1 = l[e]; e1 = e; }
        float r = expf(v1 - v0);
        float w0 = 0.5f / (1.f + r);
        float w1 = 0.5f * r / (1.f + r);
        ids[2*t]   = e0;  ids[2*t+1] = e1;
        wts[2*t]   = w0;  wts[2*t+1] = w1;
    }
}

// ---- fp32 weights -> bf16 packed B-frag order, via LDS transpose ----
__global__ __launch_bounds__(256) void k_convert_w(
    const float* __restrict__ sw1, const float* __restrict__ iw1,
    const float* __restrict__ sw2, const float* __restrict__ iw2,
    short* __restrict__ w1p, short* __restrict__ w2p) {
    __shared__ float tile[32][68];
    int bid = blockIdx.x, tid = threadIdx.x;
    const int W1B = NSLOT * 8 * 16;            // 1408
    bool isW1 = bid < W1B;
    int b = isW1 ? bid : bid - W1B;
    int NTG = isW1 ? 16 : 4;
    int KT  = isW1 ? 8 : 32;
    int NT  = isW1 ? 64 : 16;
    int Nd  = isW1 ? HIDN : OUTD;
    int ntg = b % NTG; b /= NTG;
    int kt  = b % KT;
    int slot = b / KT;
    const float* src;
    if (isW1) src = (slot < NSH) ? sw1 + (size_t)slot*DIM*HIDN  : iw1 + (size_t)(slot-NSH)*DIM*HIDN;
    else      src = (slot < NSH) ? sw2 + (size_t)slot*HIDN*OUTD : iw2 + (size_t)(slot-NSH)*HIDN*OUTD;
    {
        int tr = tid >> 3, tc = (tid & 7) * 8;
        const float* s = src + (size_t)(kt*32 + tr)*Nd + ntg*64 + tc;
        float4 v0 = *reinterpret_cast<const float4*>(s);
        float4 v1 = *reinterpret_cast<const float4*>(s + 4);
        *reinterpret_cast<float4*>(&tile[tr][tc])     = v0;
        *reinterpret_cast<float4*>(&tile[tr][tc + 4]) = v1;
    }
    __syncthreads();
    {
        int ntl = tid >> 6, lane = tid & 63;
        int n  = ntl*16 + (lane & 15);
        int k8 = (lane >> 4) * 8;
        bf16x8 o;
        #pragma unroll
        for (int j = 0; j < 8; ++j) o[j] = (short)f2bf(tile[k8 + j][n]);
        size_t gidx = (((size_t)slot*KT + kt)*NT + ntg*4 + ntl)*64 + lane;
        short* dst = isW1 ? w1p : w2p;
        reinterpret_cast<bf16x8*>(dst)[gidx] = o;
    }
}

// ---- route: LDS histogram -> 8 global atomics per block ----
__global__ __launch_bounds__(256) void k_route(
    const int* __restrict__ ids, const float* __restrict__ wts,
    int* __restrict__ cnt, int* __restrict__ ltok, float* __restrict__ lw) {
    __shared__ int lcnt[NEXP];
    __shared__ int gbase[NEXP];
    int tid = threadIdx.x;
    if (tid < NEXP) lcnt[tid] = 0;
    __syncthreads();
    int t = blockIdx.x * 256 + tid;
    int e0 = ids[2*t], e1 = ids[2*t+1];
    int p0 = atomicAdd(&lcnt[e0], 1);
    int p1 = atomicAdd(&lcnt[e1], 1);
    __syncthreads();
    if (tid < NEXP) gbase[tid] = atomicAdd(&cnt[tid], lcnt[tid]);
    __syncthreads();
    size_t o0 = (size_t)e0*TOK + gbase[e0] + p0;
    size_t o1 = (size_t)e1*TOK + gbase[e1] + p1;
    ltok[o0] = t;  lw[o0] = wts[2*t];
    ltok[o1] = t;  lw[o1] = wts[2*t+1];
}

// ---- mega-kernel v11: producer/consumer wave specialization ----
// Waves 0-3 (producers): H(c) = relu(X@W1c + b1)*tw, A from global (L1/L2-
// hot, anti-hoist), B from LDS -> 8KB LDS reads/wave-step.
// Waves 4-7 (consumers): acc2 += H(c-1) @ W2(c-1), 8KB/wave-step.
// One __syncthreads per step; stages issued at step TOP (full step of
// latency cover). LDS 76.5KB -> 2 blocks/CU; regs ~100 -> 4 waves/SIMD.
__global__ __launch_bounds__(512) void k_moe(
    const short* __restrict__ xb, const short* __restrict__ w1p, const short* __restrict__ w2p,
    const float* __restrict__ sb1, const float* __restrict__ sb2,
    const float* __restrict__ ib1, const float* __restrict__ ib2,
    const float* __restrict__ obj, const int* __restrict__ cnt,
    const int* __restrict__ ltok, const float* __restrict__ lw,
    float* __restrict__ out)
{
    __shared__ __align__(16) char Wb1[2][16384];   // [kt 0..7][ntl 0..1] x 1KB
    __shared__ __align__(16) char Wb2[2][16384];   // [nt 0..15] x 1KB
    __shared__ __align__(16) char Hs[2][4096];     // 64 x 32 bf16, rotated
    __shared__ float bias_lds[HIDN];               // b1 (4KB)
    __shared__ int   tokl[TM];
    __shared__ float twl[TM];

    const int slot = blockIdx.y;
    const int m0   = blockIdx.x * TM;
    const bool sh  = slot < NSH;
    const int e    = slot - NSH;
    int count = TOK;
    if (!sh) { count = cnt[e]; if (m0 >= count) return; }

    const int tid  = threadIdx.x;
    const int w    = tid >> 6, lane = tid & 63;
    const int lrow = lane & 15, g   = lane >> 4;
    const bool producer = w < 4;
    const int m2  = (w >> 1) & 1;                  // producer: 32-row half
    const int n16 = w & 1;                         // producer: 16-col half
    const int cw  = w - 4;                         // consumer: 64-col group

    if (tid < TM) {
        if (sh) {
            tokl[tid] = m0 + tid;
            twl[tid]  = 0.5f * obj[(size_t)(m0 + tid)*NSH + slot];
        } else {
            int p = m0 + tid;
            bool ok = p < count;
            tokl[tid] = ok ? ltok[(size_t)e*TOK + p] : 0;
            twl[tid]  = ok ? lw[(size_t)e*TOK + p] : 0.f;   // already 0.5-scaled
        }
    }
    __syncthreads();                               // tokl visible

    const char* w1base = (const char*)w1p;
    const char* w2base = (const char*)w2p;
    const float* b1v = sh ? (sb1 + slot*HIDN) : (ib1 + (size_t)e*HIDN);

    // producer X row ids (2 x 16-row frags of its 32-row half)
    int tokA0 = tokl[m2*32 + 0*16 + lrow];
    int tokA1 = tokl[m2*32 + 1*16 + lrow];

    // stage W1 chunk c: producers, 4 frags each (idx = pw*4+i; kt=idx>>1, ntl=idx&1)
    auto stage_w1 = [&](int c) {
        #pragma unroll
        for (int i = 0; i < 4; ++i) {
            int idx = w*4 + i;
            gload_lds16(
                w1base + ((((size_t)slot*8 + (idx >> 1))*64 + c*2 + (idx & 1)) << 10) + lane*16,
                Wb1[c & 1] + (idx << 10));
        }
    };
    // stage W2 chunk c: consumers, 4 frags each (nt = cw*4+i)
    auto stage_w2 = [&](int c) {
        const char* s2 = w2base + ((((size_t)slot*32 + c)*16) << 10);
        #pragma unroll
        for (int i = 0; i < 4; ++i) {
            int idx = cw*4 + i;
            gload_lds16(s2 + (idx << 10) + lane*16, Wb2[c & 1] + (idx << 10));
        }
    };

    if (producer) stage_w1(0);
    else {                                         // bias 4KB: 4 consumer waves
        gload_lds16((const char*)b1v + cw*1024 + lane*16,
                    (char*)bias_lds + cw*1024);
    }
    __syncthreads();                               // W1(0) + bias drained

    f32x4 acc2[4][4] = {};                         // consumers: 64r x 64c
    for (int s = 0; s <= NCH; ++s) {
        if (producer) {
            if (s < NCH) {
                if (s + 1 < NCH) stage_w1(s + 1);
                // prevent compiler from hoisting the X loads out of the s-loop
                asm volatile("" : "+v"(tokA0), "+v"(tokA1));
                const char* wb = Wb1[s & 1];
                f32x4 acc1[2] = {};
                #pragma unroll
                for (int kt = 0; kt < 8; ++kt) {
                    bf16x8 a0 = *reinterpret_cast<const bf16x8*>(
                        xb + (size_t)tokA0*DIM + kt*32 + g*8);
                    bf16x8 a1 = *reinterpret_cast<const bf16x8*>(
                        xb + (size_t)tokA1*DIM + kt*32 + g*8);
                    bf16x8 b = *reinterpret_cast<const bf16x8*>(
                        wb + ((kt*2 + n16) << 10) + lane*16);
                    acc1[0] = mfma16(a0, b, acc1[0]);
                    acc1[1] = mfma16(a1, b, acc1[1]);
                }
                // H = relu(acc1 + b1)*tw -> Hs[s&1]
                char* hb = Hs[s & 1];
                int col = n16*16 + lrow;
                float bias = bias_lds[s*32 + col];
                #pragma unroll
                for (int mf = 0; mf < 2; ++mf)
                    #pragma unroll
                    for (int r = 0; r < 4; ++r) {
                        int row = m2*32 + mf*16 + g*4 + r;
                        float v = fmaxf(acc1[mf][r] + bias, 0.f) * twl[row];
                        *reinterpret_cast<unsigned short*>(hb + hoff(row, col*2)) = f2bf(v);
                    }
            }
        } else {
            if (s < NCH) stage_w2(s);
            if (s >= 1) {
                const int d = s - 1;
                const char* hb = Hs[d & 1];
                const char* wb = Wb2[d & 1];
                bf16x8 a2[4];
                #pragma unroll
                for (int mf = 0; mf < 4; ++mf)
                    a2[mf] = *reinterpret_cast<const bf16x8*>(
                        hb + hoff(mf*16 + lrow, g*16));
                #pragma unroll
                for (int nf = 0; nf < 4; ++nf) {
                    bf16x8 b2 = *reinterpret_cast<const bf16x8*>(
                        wb + ((cw*4 + nf) << 10) + lane*16);
                    #pragma unroll
                    for (int mf = 0; mf < 4; ++mf)
                        acc2[mf][nf] = mfma16(a2[mf], b2, acc2[mf][nf]);
                }
            }
        }
        __syncthreads();                           // single barrier per step
    }

    // ---- epilogue: consumers write one atomic pass (+ tw*b2) ----
    if (!producer) {
        const float* b2 = sh ? (sb2 + slot*OUTD) : (ib2 + (size_t)e*OUTD);
        #pragma unroll
        for (int mf = 0; mf < 4; ++mf)
            #pragma unroll
            for (int nf = 0; nf < 4; ++nf) {
                int col = cw*64 + nf*16 + lrow;
                #pragma unroll
                for (int r = 0; r < 4; ++r) {
                    int row = mf*16 + g*4 + r;
                    if (sh || (m0 + row < count)) {
                        int t = tokl[row];
                        float v = acc2[mf][nf][r] + twl[row] * b2[col];
                        atomicAdd(&out[(size_t)t*OUTD + col], v);
                    }
                }
            }
    }
}

extern "C" void kernel_launch(void* const* d_in, const int* in_sizes, int n_in,
                              void* d_out, int out_size, void* d_ws, size_t ws_size,
                              hipStream_t stream) {
    const float* x   = (const float*)d_in[0];
    const float* obj = (const float*)d_in[1];
    const float* gw  = (const float*)d_in[2];
    const float* gb  = (const float*)d_in[3];
    const float* sw1 = (const float*)d_in[4];
    const float* sb1 = (const float*)d_in[5];
    const float* sw2 = (const float*)d_in[6];
    const float* sb2 = (const float*)d_in[7];
    const float* iw1 = (const float*)d_in[8];
    const float* ib1 = (const float*)d_in[9];
    const float* iw2 = (const float*)d_in[10];
    const float* ib2 = (const float*)d_in[11];
    float* out = (float*)d_out;
    char* ws = (char*)d_ws;
    if (ws_size < WS_NEED) return;

    short* xb   = (short*)(ws + XB_OFF);
    short* w1p  = (short*)(ws + W1P_OFF);
    short* w2p  = (short*)(ws + W2P_OFF);
    float* wts  = (float*)(ws + WTS_OFF);
    int*   ids  = (int*)  (ws + IDS_OFF);
    int*   cnt  = (int*)  (ws + CNT_OFF);
    int*   ltok = (int*)  (ws + LTOK_OFF);
    float* lwt  = (float*)(ws + LW_OFF);

    hipMemsetAsync(ws + CNT_OFF, 0, 256, stream);
    hipMemsetAsync(out, 0, (size_t)out_size * 4, stream);
    k_prep<<<TOK/4, 256, 0, stream>>>(x, gw, gb, xb, wts, ids);
    k_convert_w<<<NSLOT*8*16 + NSLOT*32*4, 256, 0, stream>>>(sw1, iw1, sw2, iw2, w1p, w2p);
    k_route<<<TOK/256, 256, 0, stream>>>(ids, wts, cnt, ltok, lwt);
    k_moe<<<dim3(TOK/TM, NSLOT), 512, 0, stream>>>(
        xb, w1p, w2p, sb1, sb2, ib1, ib2, obj, cnt, ltok, lwt, out);
}

// Round 16
// 206.275 us; speedup vs baseline: 2.6834x; 2.6834x over previous
//
#include <hip/hip_runtime.h>
#include <hip/hip_bf16.h>
#include <stdint.h>

#define TOK   16384
#define DIM   256
#define HIDN  1024
#define OUTD  256
#define NEXP  8
#define NSH   3
#define NSLOT 11
#define TM    64
#define NCH   32      // hidden chunks of 32 cols
#define HSTR  40      // H row stride in shorts (80B: 16B-aligned, <=2-way banks)

typedef short bf16x8  __attribute__((ext_vector_type(8)));
typedef float f32x4   __attribute__((ext_vector_type(4)));
typedef short short4v __attribute__((ext_vector_type(4)));

// ---- workspace layout (bytes) ----
constexpr size_t XB_OFF   = 0;                                        // T*D bf16
constexpr size_t W1P_OFF  = XB_OFF  + (size_t)TOK*DIM*2;
constexpr size_t W2P_OFF  = W1P_OFF + (size_t)NSLOT*DIM*HIDN*2;
constexpr size_t WTS_OFF  = W2P_OFF + (size_t)NSLOT*HIDN*OUTD*2;
constexpr size_t IDS_OFF  = WTS_OFF + (size_t)TOK*2*4;
constexpr size_t CNT_OFF  = IDS_OFF + (size_t)TOK*2*4;
constexpr size_t LTOK_OFF = CNT_OFF + 256;
constexpr size_t LW_OFF   = LTOK_OFF + (size_t)NEXP*TOK*4;
constexpr size_t WS_NEED  = LW_OFF + (size_t)NEXP*TOK*4;

__device__ __forceinline__ unsigned short f2bf(float f) {
    __hip_bfloat16 h = __float2bfloat16(f);
    return *reinterpret_cast<unsigned short*>(&h);
}

__device__ __forceinline__ f32x4 mfma16(bf16x8 a, bf16x8 b, f32x4 c) {
    return __builtin_amdgcn_mfma_f32_16x16x32_bf16(a, b, c, 0, 0, 0);
}

// async global->LDS: 16B/lane; global src per-lane, LDS dst uniform base.
__device__ __forceinline__ void gload_lds16(const void* g, void* l) {
    __builtin_amdgcn_global_load_lds(
        (const __attribute__((address_space(1))) unsigned int*)g,
        (__attribute__((address_space(3))) unsigned int*)l, 16, 0, 0);
}

__device__ __forceinline__ void fence_sched() { __builtin_amdgcn_sched_barrier(0); }

// ---- fused: fp32->bf16 convert of X + fp32-exact gating (one X pass) ----
__global__ __launch_bounds__(256) void k_prep(
    const float* __restrict__ x, const float* __restrict__ gw,
    const float* __restrict__ gb, short* __restrict__ xb,
    float* __restrict__ wts, int* __restrict__ ids) {
    int wid = threadIdx.x >> 6, lane = threadIdx.x & 63;
    int t = blockIdx.x * 4 + wid;
    const float* xr = x + (size_t)t * DIM;
    {
        float4 v = reinterpret_cast<const float4*>(xr)[lane];
        short4v o;
        o[0] = (short)f2bf(v.x); o[1] = (short)f2bf(v.y);
        o[2] = (short)f2bf(v.z); o[3] = (short)f2bf(v.w);
        reinterpret_cast<short4v*>(xb + (size_t)t * DIM)[lane] = o;
    }
    float acc[NEXP] = {0.f,0.f,0.f,0.f,0.f,0.f,0.f,0.f};
    #pragma unroll
    for (int i = 0; i < DIM/64; ++i) {
        int d = i*64 + lane;
        float xv = xr[d];
        const float* g = gw + (size_t)d * NEXP;
        #pragma unroll
        for (int e = 0; e < NEXP; ++e) acc[e] = fmaf(xv, g[e], acc[e]);
    }
    #pragma unroll
    for (int off = 32; off; off >>= 1) {
        #pragma unroll
        for (int e = 0; e < NEXP; ++e) acc[e] += __shfl_xor(acc[e], off, 64);
    }
    if (lane == 0) {
        float l[NEXP];
        #pragma unroll
        for (int e = 0; e < NEXP; ++e) l[e] = acc[e] + gb[e];
        int e0 = 0; float v0 = l[0];
        #pragma unroll
        for (int e = 1; e < NEXP; ++e) if (l[e] > v0) { v0 = l[e]; e0 = e; }
        int e1 = -1; float v1 = -1e30f;
        #pragma unroll
        for (int e = 0; e < NEXP; ++e) if (e != e0 && l[e] > v1) { v1 = l[e]; e1 = e; }
        float r = expf(v1 - v0);
        float w0 = 0.5f / (1.f + r);
        float w1 = 0.5f * r / (1.f + r);
        ids[2*t]   = e0;  ids[2*t+1] = e1;
        wts[2*t]   = w0;  wts[2*t+1] = w1;
    }
}

// ---- fp32 weights -> bf16 packed B-frag order, via LDS transpose ----
__global__ __launch_bounds__(256) void k_convert_w(
    const float* __restrict__ sw1, const float* __restrict__ iw1,
    const float* __restrict__ sw2, const float* __restrict__ iw2,
    short* __restrict__ w1p, short* __restrict__ w2p) {
    __shared__ float tile[32][68];
    int bid = blockIdx.x, tid = threadIdx.x;
    const int W1B = NSLOT * 8 * 16;            // 1408
    bool isW1 = bid < W1B;
    int b = isW1 ? bid : bid - W1B;
    int NTG = isW1 ? 16 : 4;
    int KT  = isW1 ? 8 : 32;
    int NT  = isW1 ? 64 : 16;
    int Nd  = isW1 ? HIDN : OUTD;
    int ntg = b % NTG; b /= NTG;
    int kt  = b % KT;
    int slot = b / KT;
    const float* src;
    if (isW1) src = (slot < NSH) ? sw1 + (size_t)slot*DIM*HIDN  : iw1 + (size_t)(slot-NSH)*DIM*HIDN;
    else      src = (slot < NSH) ? sw2 + (size_t)slot*HIDN*OUTD : iw2 + (size_t)(slot-NSH)*HIDN*OUTD;
    {
        int tr = tid >> 3, tc = (tid & 7) * 8;
        const float* s = src + (size_t)(kt*32 + tr)*Nd + ntg*64 + tc;
        float4 v0 = *reinterpret_cast<const float4*>(s);
        float4 v1 = *reinterpret_cast<const float4*>(s + 4);
        *reinterpret_cast<float4*>(&tile[tr][tc])     = v0;
        *reinterpret_cast<float4*>(&tile[tr][tc + 4]) = v1;
    }
    __syncthreads();
    {
        int ntl = tid >> 6, lane = tid & 63;
        int n  = ntl*16 + (lane & 15);
        int k8 = (lane >> 4) * 8;
        bf16x8 o;
        #pragma unroll
        for (int j = 0; j < 8; ++j) o[j] = (short)f2bf(tile[k8 + j][n]);
        size_t gidx = (((size_t)slot*KT + kt)*NT + ntg*4 + ntl)*64 + lane;
        short* dst = isW1 ? w1p : w2p;
        reinterpret_cast<bf16x8*>(dst)[gidx] = o;
    }
}

// ---- route: LDS histogram -> 8 global atomics per block ----
__global__ __launch_bounds__(256) void k_route(
    const int* __restrict__ ids, const float* __restrict__ wts,
    int* __restrict__ cnt, int* __restrict__ ltok, float* __restrict__ lw) {
    __shared__ int lcnt[NEXP];
    __shared__ int gbase[NEXP];
    int tid = threadIdx.x;
    if (tid < NEXP) lcnt[tid] = 0;
    __syncthreads();
    int t = blockIdx.x * 256 + tid;
    int e0 = ids[2*t], e1 = ids[2*t+1];
    int p0 = atomicAdd(&lcnt[e0], 1);
    int p1 = atomicAdd(&lcnt[e1], 1);
    __syncthreads();
    if (tid < NEXP) gbase[tid] = atomicAdd(&cnt[tid], lcnt[tid]);
    __syncthreads();
    size_t o0 = (size_t)e0*TOK + gbase[e0] + p0;
    size_t o1 = (size_t)e1*TOK + gbase[e1] + p1;
    ltok[o0] = t;  lw[o0] = wts[2*t];
    ltok[o1] = t;  lw[o1] = wts[2*t+1];
}

// ---- mega-kernel v12: r14 structure, A hoisted to registers, padded H ----
// r14 re-read chunk-invariant A-frags from LDS every chunk (8KB of 22KB per
// wave-chunk). areg[8]=32 VGPR holds them; Xs buffer deleted (LDS 73->42.5KB).
// H rows padded to 80B (16B-aligned; <=2-way banks both ways; VALU-written
// so padding legal). Same split counted-vmcnt staging + balanced 2D grid.
__global__ __launch_bounds__(512) void k_moe(
    const short* __restrict__ xb, const short* __restrict__ w1p, const short* __restrict__ w2p,
    const float* __restrict__ sb1, const float* __restrict__ sb2,
    const float* __restrict__ ib1, const float* __restrict__ ib2,
    const float* __restrict__ obj, const int* __restrict__ cnt,
    const int* __restrict__ ltok, const float* __restrict__ lw,
    float* __restrict__ out)
{
    __shared__ __align__(16) char Wb1[16384];      // [kt 0..7][ntl 0..1] x 1KB
    __shared__ __align__(16) char Wb2[16384];      // [nt 0..15] x 1KB
    __shared__ __align__(16) short Hs[TM * HSTR];  // 64 x 40 shorts (80B stride)
    __shared__ float bias_lds[HIDN];               // b1 (4KB)
    __shared__ int   tokl[TM];
    __shared__ float twl[TM];

    const int slot = blockIdx.y;
    const int m0   = blockIdx.x * TM;
    const bool sh  = slot < NSH;
    const int e    = slot - NSH;
    int count = TOK;
    if (!sh) { count = cnt[e]; if (m0 >= count) return; }

    const int tid  = threadIdx.x;
    const int w    = tid >> 6, lane = tid & 63;
    const int wm   = w >> 1,   wn   = w & 1;       // phase-1: 4m x 2n (16r x 16c)
    const int pm   = w >> 2,   pn   = w & 3;       // phase-2: 2m x 4n (32r x 64c)
    const int lrow = lane & 15, g   = lane >> 4;

    if (tid < TM) {
        if (sh) {
            tokl[tid] = m0 + tid;
            twl[tid]  = 0.5f * obj[(size_t)(m0 + tid)*NSH + slot];
        } else {
            int p = m0 + tid;
            bool ok = p < count;
            tokl[tid] = ok ? ltok[(size_t)e*TOK + p] : 0;
            twl[tid]  = ok ? lw[(size_t)e*TOK + p] : 0.f;   // already 0.5-scaled
        }
    }
    __syncthreads();                               // tokl visible

    const char* w1base = (const char*)w1p;
    const char* w2base = (const char*)w2p;
    const float* b1v = sh ? (sb1 + slot*HIDN) : (ib1 + (size_t)e*HIDN);

    // ---- A-frags of this wave -> registers, once (chunk-invariant) ----
    const int tokA = tokl[wm*16 + lrow];
    bf16x8 areg[8];
    #pragma unroll
    for (int kt = 0; kt < 8; ++kt)
        areg[kt] = *reinterpret_cast<const bf16x8*>(
            xb + (size_t)tokA*DIM + kt*32 + g*8);

    // bias 4KB: waves 0..3
    if (w < 4)
        gload_lds16((const char*)b1v + w*1024 + lane*16, (char*)bias_lds + w*1024);

    // stage W1 chunk c (16KB): wave w stages (kt=w, ntl=0,1)
    auto stage_w1 = [&](int c) {
        #pragma unroll
        for (int i = 0; i < 2; ++i)
            gload_lds16(
                w1base + ((((size_t)slot*8 + w)*64 + c*2 + i) << 10) + lane*16,
                Wb1 + ((w*2 + i) << 10));
    };
    // stage W2 chunk c (16KB): wave w stages nt = w*2, w*2+1
    auto stage_w2 = [&](int c) {
        const char* s2 = w2base + ((((size_t)slot*32 + c)*16) << 10);
        #pragma unroll
        for (int i = 0; i < 2; ++i)
            gload_lds16(s2 + ((w*2 + i) << 10) + lane*16, Wb2 + ((w*2 + i) << 10));
    };
    stage_w1(0);
    stage_w2(0);
    // hard drain: areg/bias/stage(0) complete; loop VMEM = staging only
    asm volatile("s_waitcnt vmcnt(0) lgkmcnt(0)" ::: "memory");
    __syncthreads();

    f32x4 acc2[2][4] = {};                         // phase-2 wave tile 32 x 64
    for (int c = 0; c < NCH; ++c) {
        if (c > 0) {
            stage_w2(c);                           // W2 buf free since last barrier
            fence_sched();
            asm volatile("s_waitcnt vmcnt(2)" ::: "memory");   // W1(c) landed
            fence_sched();
            __builtin_amdgcn_s_barrier();
            fence_sched();
        }

        // ---- phase 1 (4m x 2n): acc1 = X(regs) @ W1c, wave 16r x 16c ----
        f32x4 acc1 = {};
        #pragma unroll
        for (int kt = 0; kt < 8; ++kt) {
            bf16x8 b = *reinterpret_cast<const bf16x8*>(
                Wb1 + ((kt*2 + wn) << 10) + lane*16);
            acc1 = mfma16(areg[kt], b, acc1);
        }
        // H = relu(acc1 + b1)*tw -> padded LDS bf16
        {
            int col = wn*16 + lrow;
            float bias = bias_lds[c*32 + col];
            #pragma unroll
            for (int r = 0; r < 4; ++r) {
                int row = wm*16 + g*4 + r;
                float v = fmaxf(acc1[r] + bias, 0.f) * twl[row];
                Hs[row*HSTR + col] = (short)f2bf(v);
            }
        }
        fence_sched();
        asm volatile("s_waitcnt lgkmcnt(0)" ::: "memory");   // W1 reads + H writes done
        fence_sched();
        __builtin_amdgcn_s_barrier();
        fence_sched();

        if (c + 1 < NCH) stage_w1(c + 1);          // hides under phase 2
        fence_sched();
        if (c + 1 < NCH) { asm volatile("s_waitcnt vmcnt(2)" ::: "memory"); }
        else             { asm volatile("s_waitcnt vmcnt(0)" ::: "memory"); }
        fence_sched();
        __builtin_amdgcn_s_barrier();              // W2(c) + H visible
        fence_sched();

        // ---- phase 2 (2m x 4n): acc2 += H(64x32) @ W2c(32x256), 32r x 64c ----
        {
            bf16x8 a2[2];
            #pragma unroll
            for (int mf = 0; mf < 2; ++mf)
                a2[mf] = *reinterpret_cast<const bf16x8*>(
                    Hs + (pm*32 + mf*16 + lrow)*HSTR + g*8);
            #pragma unroll
            for (int nf = 0; nf < 4; ++nf) {
                bf16x8 b2 = *reinterpret_cast<const bf16x8*>(
                    Wb2 + ((pn*4 + nf) << 10) + lane*16);
                #pragma unroll
                for (int mf = 0; mf < 2; ++mf)
                    acc2[mf][nf] = mfma16(a2[mf], b2, acc2[mf][nf]);
            }
        }
        fence_sched();
        __builtin_amdgcn_s_barrier();   // phase-2 reads retired -> W2/H reusable
        fence_sched();
    }

    // ---- epilogue: one atomic pass (+ tw*b2), phase-2 mapping ----
    {
        const float* b2 = sh ? (sb2 + slot*OUTD) : (ib2 + (size_t)e*OUTD);
        #pragma unroll
        for (int mf = 0; mf < 2; ++mf)
            #pragma unroll
            for (int nf = 0; nf < 4; ++nf) {
                int col = pn*64 + nf*16 + lrow;
                #pragma unroll
                for (int r = 0; r < 4; ++r) {
                    int row = pm*32 + mf*16 + g*4 + r;
                    if (sh || (m0 + row < count)) {
                        int t = tokl[row];
                        float v = acc2[mf][nf][r] + twl[row] * b2[col];
                        atomicAdd(&out[(size_t)t*OUTD + col], v);
                    }
                }
            }
    }
}

extern "C" void kernel_launch(void* const* d_in, const int* in_sizes, int n_in,
                              void* d_out, int out_size, void* d_ws, size_t ws_size,
                              hipStream_t stream) {
    const float* x   = (const float*)d_in[0];
    const float* obj = (const float*)d_in[1];
    const float* gw  = (const float*)d_in[2];
    const float* gb  = (const float*)d_in[3];
    const float* sw1 = (const float*)d_in[4];
    const float* sb1 = (const float*)d_in[5];
    const float* sw2 = (const float*)d_in[6];
    const float* sb2 = (const float*)d_in[7];
    const float* iw1 = (const float*)d_in[8];
    const float* ib1 = (const float*)d_in[9];
    const float* iw2 = (const float*)d_in[10];
    const float* ib2 = (const float*)d_in[11];
    float* out = (float*)d_out;
    char* ws = (char*)d_ws;
    if (ws_size < WS_NEED) return;

    short* xb   = (short*)(ws + XB_OFF);
    short* w1p  = (short*)(ws + W1P_OFF);
    short* w2p  = (short*)(ws + W2P_OFF);
    float* wts  = (float*)(ws + WTS_OFF);
    int*   ids  = (int*)  (ws + IDS_OFF);
    int*   cnt  = (int*)  (ws + CNT_OFF);
    int*   ltok = (int*)  (ws + LTOK_OFF);
    float* lwt  = (float*)(ws + LW_OFF);

    hipMemsetAsync(ws + CNT_OFF, 0, 256, stream);
    hipMemsetAsync(out, 0, (size_t)out_size * 4, stream);
    k_prep<<<TOK/4, 256, 0, stream>>>(x, gw, gb, xb, wts, ids);
    k_convert_w<<<NSLOT*8*16 + NSLOT*32*4, 256, 0, stream>>>(sw1, iw1, sw2, iw2, w1p, w2p);
    k_route<<<TOK/256, 256, 0, stream>>>(ids, wts, cnt, ltok, lwt);
    k_moe<<<dim3(TOK/TM, NSLOT), 512, 0, stream>>>(
        xb, w1p, w2p, sb1, sb2, ib1, ib2, obj, cnt, ltok, lwt, out);
}

// Round 17
// 203.815 us; speedup vs baseline: 2.7158x; 1.0121x over previous
//
#include <hip/hip_runtime.h>
#include <hip/hip_bf16.h>
#include <stdint.h>

#define TOK   16384
#define DIM   256
#define HIDN  1024
#define OUTD  256
#define NEXP  8
#define NSH   3
#define NSLOT 11
#define TM    64
#define NCH   32      // hidden chunks of 32 cols
#define HSTR  40      // H row stride in shorts (80B: 16B-aligned, <=2-way banks)

typedef short bf16x8  __attribute__((ext_vector_type(8)));
typedef float f32x4   __attribute__((ext_vector_type(4)));
typedef short short4v __attribute__((ext_vector_type(4)));

// ---- workspace layout (bytes) ----
constexpr size_t XB_OFF   = 0;                                        // T*D bf16
constexpr size_t W1P_OFF  = XB_OFF  + (size_t)TOK*DIM*2;
constexpr size_t W2P_OFF  = W1P_OFF + (size_t)NSLOT*DIM*HIDN*2;
constexpr size_t WTS_OFF  = W2P_OFF + (size_t)NSLOT*HIDN*OUTD*2;
constexpr size_t IDS_OFF  = WTS_OFF + (size_t)TOK*2*4;
constexpr size_t CNT_OFF  = IDS_OFF + (size_t)TOK*2*4;
constexpr size_t LTOK_OFF = CNT_OFF + 256;
constexpr size_t LW_OFF   = LTOK_OFF + (size_t)NEXP*TOK*4;
constexpr size_t WS_NEED  = LW_OFF + (size_t)NEXP*TOK*4;

__device__ __forceinline__ unsigned short f2bf(float f) {
    __hip_bfloat16 h = __float2bfloat16(f);
    return *reinterpret_cast<unsigned short*>(&h);
}

__device__ __forceinline__ f32x4 mfma16(bf16x8 a, bf16x8 b, f32x4 c) {
    return __builtin_amdgcn_mfma_f32_16x16x32_bf16(a, b, c, 0, 0, 0);
}

// async global->LDS: 16B/lane; global src per-lane, LDS dst uniform base.
__device__ __forceinline__ void gload_lds16(const void* g, void* l) {
    __builtin_amdgcn_global_load_lds(
        (const __attribute__((address_space(1))) unsigned int*)g,
        (__attribute__((address_space(3))) unsigned int*)l, 16, 0, 0);
}

__device__ __forceinline__ void fence_sched() { __builtin_amdgcn_sched_barrier(0); }

// ---- fused: fp32->bf16 convert of X + fp32-exact gating (one X pass) ----
__global__ __launch_bounds__(256) void k_prep(
    const float* __restrict__ x, const float* __restrict__ gw,
    const float* __restrict__ gb, short* __restrict__ xb,
    float* __restrict__ wts, int* __restrict__ ids) {
    int wid = threadIdx.x >> 6, lane = threadIdx.x & 63;
    int t = blockIdx.x * 4 + wid;
    const float* xr = x + (size_t)t * DIM;
    {
        float4 v = reinterpret_cast<const float4*>(xr)[lane];
        short4v o;
        o[0] = (short)f2bf(v.x); o[1] = (short)f2bf(v.y);
        o[2] = (short)f2bf(v.z); o[3] = (short)f2bf(v.w);
        reinterpret_cast<short4v*>(xb + (size_t)t * DIM)[lane] = o;
    }
    float acc[NEXP] = {0.f,0.f,0.f,0.f,0.f,0.f,0.f,0.f};
    #pragma unroll
    for (int i = 0; i < DIM/64; ++i) {
        int d = i*64 + lane;
        float xv = xr[d];
        const float* g = gw + (size_t)d * NEXP;
        #pragma unroll
        for (int e = 0; e < NEXP; ++e) acc[e] = fmaf(xv, g[e], acc[e]);
    }
    #pragma unroll
    for (int off = 32; off; off >>= 1) {
        #pragma unroll
        for (int e = 0; e < NEXP; ++e) acc[e] += __shfl_xor(acc[e], off, 64);
    }
    if (lane == 0) {
        float l[NEXP];
        #pragma unroll
        for (int e = 0; e < NEXP; ++e) l[e] = acc[e] + gb[e];
        int e0 = 0; float v0 = l[0];
        #pragma unroll
        for (int e = 1; e < NEXP; ++e) if (l[e] > v0) { v0 = l[e]; e0 = e; }
        int e1 = -1; float v1 = -1e30f;
        #pragma unroll
        for (int e = 0; e < NEXP; ++e) if (e != e0 && l[e] > v1) { v1 = l[e]; e1 = e; }
        float r = expf(v1 - v0);
        float w0 = 0.5f / (1.f + r);
        float w1 = 0.5f * r / (1.f + r);
        ids[2*t]   = e0;  ids[2*t+1] = e1;
        wts[2*t]   = w0;  wts[2*t+1] = w1;
    }
}

// ---- fp32 weights -> bf16 packed B-frag order, via LDS transpose ----
__global__ __launch_bounds__(256) void k_convert_w(
    const float* __restrict__ sw1, const float* __restrict__ iw1,
    const float* __restrict__ sw2, const float* __restrict__ iw2,
    short* __restrict__ w1p, short* __restrict__ w2p) {
    __shared__ float tile[32][68];
    int bid = blockIdx.x, tid = threadIdx.x;
    const int W1B = NSLOT * 8 * 16;            // 1408
    bool isW1 = bid < W1B;
    int b = isW1 ? bid : bid - W1B;
    int NTG = isW1 ? 16 : 4;
    int KT  = isW1 ? 8 : 32;
    int NT  = isW1 ? 64 : 16;
    int Nd  = isW1 ? HIDN : OUTD;
    int ntg = b % NTG; b /= NTG;
    int kt  = b % KT;
    int slot = b / KT;
    const float* src;
    if (isW1) src = (slot < NSH) ? sw1 + (size_t)slot*DIM*HIDN  : iw1 + (size_t)(slot-NSH)*DIM*HIDN;
    else      src = (slot < NSH) ? sw2 + (size_t)slot*HIDN*OUTD : iw2 + (size_t)(slot-NSH)*HIDN*OUTD;
    {
        int tr = tid >> 3, tc = (tid & 7) * 8;
        const float* s = src + (size_t)(kt*32 + tr)*Nd + ntg*64 + tc;
        float4 v0 = *reinterpret_cast<const float4*>(s);
        float4 v1 = *reinterpret_cast<const float4*>(s + 4);
        *reinterpret_cast<float4*>(&tile[tr][tc])     = v0;
        *reinterpret_cast<float4*>(&tile[tr][tc + 4]) = v1;
    }
    __syncthreads();
    {
        int ntl = tid >> 6, lane = tid & 63;
        int n  = ntl*16 + (lane & 15);
        int k8 = (lane >> 4) * 8;
        bf16x8 o;
        #pragma unroll
        for (int j = 0; j < 8; ++j) o[j] = (short)f2bf(tile[k8 + j][n]);
        size_t gidx = (((size_t)slot*KT + kt)*NT + ntg*4 + ntl)*64 + lane;
        short* dst = isW1 ? w1p : w2p;
        reinterpret_cast<bf16x8*>(dst)[gidx] = o;
    }
}

// ---- route: LDS histogram -> 8 global atomics per block ----
__global__ __launch_bounds__(256) void k_route(
    const int* __restrict__ ids, const float* __restrict__ wts,
    int* __restrict__ cnt, int* __restrict__ ltok, float* __restrict__ lw) {
    __shared__ int lcnt[NEXP];
    __shared__ int gbase[NEXP];
    int tid = threadIdx.x;
    if (tid < NEXP) lcnt[tid] = 0;
    __syncthreads();
    int t = blockIdx.x * 256 + tid;
    int e0 = ids[2*t], e1 = ids[2*t+1];
    int p0 = atomicAdd(&lcnt[e0], 1);
    int p1 = atomicAdd(&lcnt[e1], 1);
    __syncthreads();
    if (tid < NEXP) gbase[tid] = atomicAdd(&cnt[tid], lcnt[tid]);
    __syncthreads();
    size_t o0 = (size_t)e0*TOK + gbase[e0] + p0;
    size_t o1 = (size_t)e1*TOK + gbase[e1] + p1;
    ltok[o0] = t;  lw[o0] = wts[2*t];
    ltok[o1] = t;  lw[o1] = wts[2*t+1];
}

// ---- mega-kernel v13: r16 + FULLY double-buffered W1/W2, 2-chunk W1 lead.
// Issue-order invariant entering chunk c: [W1(c), W2(c), W1(c+1)]; top of c
// issues W2(c+1) then ONE vmcnt(4) covers both W1(c) (1.7 chunks of latency
// cover) and W2(c) (1 chunk). W1(c+2) issued right after the phase-1 barrier
// (buffer just freed). 3 barriers/chunk (was 4), zero expected stage-stall.
// LDS 74.3KB -> still 2 blocks/CU.
__global__ __launch_bounds__(512) void k_moe(
    const short* __restrict__ xb, const short* __restrict__ w1p, const short* __restrict__ w2p,
    const float* __restrict__ sb1, const float* __restrict__ sb2,
    const float* __restrict__ ib1, const float* __restrict__ ib2,
    const float* __restrict__ obj, const int* __restrict__ cnt,
    const int* __restrict__ ltok, const float* __restrict__ lw,
    float* __restrict__ out)
{
    __shared__ __align__(16) char Wb1[2][16384];   // [kt 0..7][ntl 0..1] x 1KB
    __shared__ __align__(16) char Wb2[2][16384];   // [nt 0..15] x 1KB
    __shared__ __align__(16) short Hs[TM * HSTR];  // 64 x 40 shorts (80B stride)
    __shared__ float bias_lds[HIDN];               // b1 (4KB)
    __shared__ int   tokl[TM];
    __shared__ float twl[TM];

    const int slot = blockIdx.y;
    const int m0   = blockIdx.x * TM;
    const bool sh  = slot < NSH;
    const int e    = slot - NSH;
    int count = TOK;
    if (!sh) { count = cnt[e]; if (m0 >= count) return; }

    const int tid  = threadIdx.x;
    const int w    = tid >> 6, lane = tid & 63;
    const int wm   = w >> 1,   wn   = w & 1;       // phase-1: 4m x 2n (16r x 16c)
    const int pm   = w >> 2,   pn   = w & 3;       // phase-2: 2m x 4n (32r x 64c)
    const int lrow = lane & 15, g   = lane >> 4;

    if (tid < TM) {
        if (sh) {
            tokl[tid] = m0 + tid;
            twl[tid]  = 0.5f * obj[(size_t)(m0 + tid)*NSH + slot];
        } else {
            int p = m0 + tid;
            bool ok = p < count;
            tokl[tid] = ok ? ltok[(size_t)e*TOK + p] : 0;
            twl[tid]  = ok ? lw[(size_t)e*TOK + p] : 0.f;   // already 0.5-scaled
        }
    }
    __syncthreads();                               // tokl visible

    const char* w1base = (const char*)w1p;
    const char* w2base = (const char*)w2p;
    const float* b1v = sh ? (sb1 + slot*HIDN) : (ib1 + (size_t)e*HIDN);

    // ---- A-frags of this wave -> registers, once (chunk-invariant) ----
    const int tokA = tokl[wm*16 + lrow];
    bf16x8 areg[8];
    #pragma unroll
    for (int kt = 0; kt < 8; ++kt)
        areg[kt] = *reinterpret_cast<const bf16x8*>(
            xb + (size_t)tokA*DIM + kt*32 + g*8);

    // bias 4KB: waves 0..3
    if (w < 4)
        gload_lds16((const char*)b1v + w*1024 + lane*16, (char*)bias_lds + w*1024);

    // stage W1 chunk c (16KB) into buf: wave w stages (kt=w, ntl=0,1)
    auto stage_w1 = [&](int c, int buf) {
        #pragma unroll
        for (int i = 0; i < 2; ++i)
            gload_lds16(
                w1base + ((((size_t)slot*8 + w)*64 + c*2 + i) << 10) + lane*16,
                Wb1[buf] + ((w*2 + i) << 10));
    };
    // stage W2 chunk c (16KB) into buf: wave w stages nt = w*2, w*2+1
    auto stage_w2 = [&](int c, int buf) {
        const char* s2 = w2base + ((((size_t)slot*32 + c)*16) << 10);
        #pragma unroll
        for (int i = 0; i < 2; ++i)
            gload_lds16(s2 + ((w*2 + i) << 10) + lane*16, Wb2[buf] + ((w*2 + i) << 10));
    };

    // hard drain: areg/bias complete; all later VMEM is staging (exact counts)
    asm volatile("s_waitcnt vmcnt(0) lgkmcnt(0)" ::: "memory");
    __syncthreads();

    // prologue stages, order matters for vmcnt counting: W1(0), W2(0), W1(1)
    stage_w1(0, 0);
    stage_w2(0, 0);
    stage_w1(1, 1);

    f32x4 acc2[2][4] = {};                         // phase-2 wave tile 32 x 64
    for (int c = 0; c < NCH; ++c) {
        const int p = c & 1;
        // top: issue W2(c+1), then ONE counted wait for W1(c)+W2(c)
        if (c + 1 < NCH) {
            stage_w2(c + 1, p ^ 1);
            fence_sched();
            asm volatile("s_waitcnt vmcnt(4)" ::: "memory");
        } else {
            fence_sched();
            asm volatile("s_waitcnt vmcnt(0)" ::: "memory");
        }
        fence_sched();
        __builtin_amdgcn_s_barrier();              // W1(c), W2(c) visible to all
        fence_sched();

        // ---- phase 1 (4m x 2n): acc1 = X(regs) @ W1c, wave 16r x 16c ----
        f32x4 acc1 = {};
        #pragma unroll
        for (int kt = 0; kt < 8; ++kt) {
            bf16x8 b = *reinterpret_cast<const bf16x8*>(
                Wb1[p] + ((kt*2 + wn) << 10) + lane*16);
            acc1 = mfma16(areg[kt], b, acc1);
        }
        // H = relu(acc1 + b1)*tw -> padded LDS bf16
        {
            int col = wn*16 + lrow;
            float bias = bias_lds[c*32 + col];
            #pragma unroll
            for (int r = 0; r < 4; ++r) {
                int row = wm*16 + g*4 + r;
                float v = fmaxf(acc1[r] + bias, 0.f) * twl[row];
                Hs[row*HSTR + col] = (short)f2bf(v);
            }
        }
        fence_sched();
        asm volatile("s_waitcnt lgkmcnt(0)" ::: "memory");   // W1 reads + H writes done
        fence_sched();
        __builtin_amdgcn_s_barrier();              // H visible; Wb1[p] free
        fence_sched();

        if (c + 2 < NCH) stage_w1(c + 2, p);       // 2-chunk lead for W1
        fence_sched();

        // ---- phase 2 (2m x 4n): acc2 += H(64x32) @ W2c(32x256), 32r x 64c ----
        // (W2(c) landed per top wait; H per barrier -- no wait needed here)
        {
            bf16x8 a2[2];
            #pragma unroll
            for (int mf = 0; mf < 2; ++mf)
                a2[mf] = *reinterpret_cast<const bf16x8*>(
                    Hs + (pm*32 + mf*16 + lrow)*HSTR + g*8);
            #pragma unroll
            for (int nf = 0; nf < 4; ++nf) {
                bf16x8 b2 = *reinterpret_cast<const bf16x8*>(
                    Wb2[p] + ((pn*4 + nf) << 10) + lane*16);
                #pragma unroll
                for (int mf = 0; mf < 2; ++mf)
                    acc2[mf][nf] = mfma16(a2[mf], b2, acc2[mf][nf]);
            }
        }
        fence_sched();
        __builtin_amdgcn_s_barrier();   // phase-2 reads retired -> H/Wb2[p] reusable
        fence_sched();
    }

    // ---- epilogue: one atomic pass (+ tw*b2), phase-2 mapping ----
    {
        const float* b2 = sh ? (sb2 + slot*OUTD) : (ib2 + (size_t)e*OUTD);
        #pragma unroll
        for (int mf = 0; mf < 2; ++mf)
            #pragma unroll
            for (int nf = 0; nf < 4; ++nf) {
                int col = pn*64 + nf*16 + lrow;
                #pragma unroll
                for (int r = 0; r < 4; ++r) {
                    int row = pm*32 + mf*16 + g*4 + r;
                    if (sh || (m0 + row < count)) {
                        int t = tokl[row];
                        float v = acc2[mf][nf][r] + twl[row] * b2[col];
                        atomicAdd(&out[(size_t)t*OUTD + col], v);
                    }
                }
            }
    }
}

extern "C" void kernel_launch(void* const* d_in, const int* in_sizes, int n_in,
                              void* d_out, int out_size, void* d_ws, size_t ws_size,
                              hipStream_t stream) {
    const float* x   = (const float*)d_in[0];
    const float* obj = (const float*)d_in[1];
    const float* gw  = (const float*)d_in[2];
    const float* gb  = (const float*)d_in[3];
    const float* sw1 = (const float*)d_in[4];
    const float* sb1 = (const float*)d_in[5];
    const float* sw2 = (const float*)d_in[6];
    const float* sb2 = (const float*)d_in[7];
    const float* iw1 = (const float*)d_in[8];
    const float* ib1 = (const float*)d_in[9];
    const float* iw2 = (const float*)d_in[10];
    const float* ib2 = (const float*)d_in[11];
    float* out = (float*)d_out;
    char* ws = (char*)d_ws;
    if (ws_size < WS_NEED) return;

    short* xb   = (short*)(ws + XB_OFF);
    short* w1p  = (short*)(ws + W1P_OFF);
    short* w2p  = (short*)(ws + W2P_OFF);
    float* wts  = (float*)(ws + WTS_OFF);
    int*   ids  = (int*)  (ws + IDS_OFF);
    int*   cnt  = (int*)  (ws + CNT_OFF);
    int*   ltok = (int*)  (ws + LTOK_OFF);
    float* lwt  = (float*)(ws + LW_OFF);

    hipMemsetAsync(ws + CNT_OFF, 0, 256, stream);
    hipMemsetAsync(out, 0, (size_t)out_size * 4, stream);
    k_prep<<<TOK/4, 256, 0, stream>>>(x, gw, gb, xb, wts, ids);
    k_convert_w<<<NSLOT*8*16 + NSLOT*32*4, 256, 0, stream>>>(sw1, iw1, sw2, iw2, w1p, w2p);
    k_route<<<TOK/256, 256, 0, stream>>>(ids, wts, cnt, ltok, lwt);
    k_moe<<<dim3(TOK/TM, NSLOT), 512, 0, stream>>>(
        xb, w1p, w2p, sb1, sb2, ib1, ib2, obj, cnt, ltok, lwt, out);
}